// Round 14
// baseline (1366.673 us; speedup 1.0000x reference)
//
#include <hip/hip_runtime.h>
#include <hip/hip_bf16.h>

// Problem constants
#define NB   32
#define LL   320
#define CC   768
#define NH   12
#define DHD  64
#define LT   64
#define LSN  256
#define NKEEP 180
#define NREM  76
#define LP   244
#define ADH  64
#define C4   3072

typedef __attribute__((ext_vector_type(8))) short s16x8;
typedef __attribute__((ext_vector_type(4))) float f32x4;

__device__ __forceinline__ ushort f2b(float f){
  union { __hip_bfloat16 h; ushort u; } cv;
  cv.h = __float2bfloat16(f);
  return cv.u;
}

__device__ __forceinline__ void glds16(const ushort* g, ushort* l){
  __builtin_amdgcn_global_load_lds(
      (const __attribute__((address_space(1))) void*)g,
      (__attribute__((address_space(3))) void*)l, 16, 0, 0);
}

// ---------------- reductions ----------------
__device__ __forceinline__ float blk_sum(float v, float* sh){
  #pragma unroll
  for (int o = 32; o > 0; o >>= 1) v += __shfl_down(v, o, 64);
  int w = threadIdx.x >> 6;
  if ((threadIdx.x & 63) == 0) sh[w] = v;
  __syncthreads();
  float r = sh[0] + sh[1] + sh[2] + sh[3];
  __syncthreads();
  return r;
}

// ---------------- LayerNorm, both streams in one launch ----------------
__global__ __launch_bounds__(256) void ln12_k(const float* __restrict__ x0,
                                              const float* __restrict__ x1,
                                              int rowsplit,
                                              const float* __restrict__ g,
                                              const float* __restrict__ be,
                                              float* __restrict__ y,
                                              ushort* __restrict__ yb,
                                              float* __restrict__ lnt){
  __shared__ float sh[4];
  int row = blockIdx.x;
  const float* xr = (row < rowsplit) ? x0 + (size_t)row * CC
                                     : x1 + (size_t)(row - rowsplit) * CC;
  int t = threadIdx.x;
  float v0 = xr[t], v1 = xr[t + 256], v2 = xr[t + 512];
  float m = blk_sum(v0 + v1 + v2, sh) * (1.0f / 768.0f);
  float d0 = v0 - m, d1 = v1 - m, d2 = v2 - m;
  float var = blk_sum(d0*d0 + d1*d1 + d2*d2, sh) * (1.0f / 768.0f);
  float rs = rsqrtf(var + 1e-5f);
  float o0 = d0 * rs * g[t]       + be[t];
  float o1 = d1 * rs * g[t + 256] + be[t + 256];
  float o2 = d2 * rs * g[t + 512] + be[t + 512];
  float* yr = y + (size_t)row * CC;
  yr[t] = o0; yr[t + 256] = o1; yr[t + 512] = o2;
  if (yb){
    ushort* yr2 = yb + (size_t)row * CC;
    yr2[t] = f2b(o0); yr2[t + 256] = f2b(o1); yr2[t + 512] = f2b(o2);
  }
  if (lnt){
    int i = row % LL;
    if (i < 64){
      float* lr = lnt + ((size_t)(row / LL) * 64 + i) * CC;
      lr[t] = o0; lr[t + 256] = o1; lr[t + 512] = o2;
    }
  }
}

// ---------------- f32 GEMM body (bit-identical k-order), dual-job ----------------
__device__ __forceinline__ void f32gemm_body(
    float* As, float* Bs, int bx, int by,
    const float* __restrict__ A1, const float* __restrict__ W1,
    float* __restrict__ C1, ushort* __restrict__ Cb1,
    const float* __restrict__ A2, const float* __restrict__ W2,
    float* __restrict__ C2,
    int K, int ldw, int ldc, int ysplit)
{
  const int t = threadIdx.x;
  const int tx = t & 15, ty = t >> 4;
  const int n0 = bx * 128;
  const float* A; const float* W; float* Cm; ushort* Cb; int m0;
  if (by < ysplit){ A = A1; W = W1; Cm = C1; Cb = Cb1; m0 = by * 128; }
  else            { A = A2; W = W2; Cm = C2; Cb = nullptr; m0 = (by - ysplit) * 128; }

  float acc[8][8] = {};
  for (int k0 = 0; k0 < K; k0 += 32){
    #pragma unroll
    for (int q = 0; q < 4; q++){
      int idx = t + q*256;
      int m = idx & 127, kq = idx >> 7;
      float4 v = *reinterpret_cast<const float4*>(A + (size_t)(m0+m)*K + k0 + kq*4);
      As[(kq*4+0)*128 + m] = v.x; As[(kq*4+1)*128 + m] = v.y;
      As[(kq*4+2)*128 + m] = v.z; As[(kq*4+3)*128 + m] = v.w;
    }
    #pragma unroll
    for (int q = 0; q < 4; q++){
      int idx = t + q*256;
      int kr = idx >> 5, nq = idx & 31;
      float4 v = *reinterpret_cast<const float4*>(W + (size_t)(k0+kr)*ldw + n0 + nq*4);
      *reinterpret_cast<float4*>(&Bs[kr*128 + nq*4]) = v;
    }
    __syncthreads();
    #pragma unroll
    for (int kk = 0; kk < 32; kk++){
      float a[8], b[8];
      *reinterpret_cast<float4*>(&a[0]) = *reinterpret_cast<float4*>(&As[kk*128 + ty*4]);
      *reinterpret_cast<float4*>(&a[4]) = *reinterpret_cast<float4*>(&As[kk*128 + 64 + ty*4]);
      *reinterpret_cast<float4*>(&b[0]) = *reinterpret_cast<float4*>(&Bs[kk*128 + tx*4]);
      *reinterpret_cast<float4*>(&b[4]) = *reinterpret_cast<float4*>(&Bs[kk*128 + 64 + tx*4]);
      #pragma unroll
      for (int i = 0; i < 8; i++)
        #pragma unroll
        for (int j = 0; j < 8; j++)
          acc[i][j] = fmaf(a[i], b[j], acc[i][j]);
    }
    __syncthreads();
  }
  #pragma unroll
  for (int i = 0; i < 8; i++){
    int m = m0 + ty*4 + (i & 3) + (i >> 2) * 64;
    #pragma unroll
    for (int j = 0; j < 8; j++){
      int n = n0 + tx*4 + (j & 3) + (j >> 2) * 64;
      float v = acc[i][j];
      Cm[(size_t)m * ldc + n] = v;
      if (Cb) Cb[(size_t)m * ldc + n] = f2b(v);
    }
  }
}

// ---------------- bf16 MFMA GEMM body (glds16 staging, fused 2nd segment, dual C) ----------------
template<bool GELU, bool ACC, bool OBF>
__device__ __forceinline__ void mg_body(
    ushort* Asm, ushort* Bsm, int bx, int by,
    const ushort* __restrict__ A, const ushort* __restrict__ Wt,
    const float* __restrict__ bias, void* __restrict__ Cp,
    int M, int N, int K,
    const float* __restrict__ res0, const float* __restrict__ res1, int Mhalf,
    const ushort* __restrict__ A2_0, const ushort* __restrict__ A2_1,
    const ushort* __restrict__ W2t, int K2, const float* __restrict__ bias2,
    void* __restrict__ Cp1)
{
  const int t = threadIdx.x;
  const int m0 = by * 128, n0 = bx * 128;
  const int wave = t >> 6, lane = t & 63;
  const int wrow = wave >> 1, wcol = wave & 1;
  const int lr = lane & 15, ks = lane >> 4;
  const int srow = lane >> 2, scp = lane & 3;

  f32x4 acc[4][4];
  #pragma unroll
  for (int i = 0; i < 4; i++)
    #pragma unroll
    for (int j = 0; j < 4; j++)
      #pragma unroll
      for (int r = 0; r < 4; r++) acc[i][j][r] = 0.f;

  const int nseg = W2t ? 2 : 1;
  for (int seg = 0; seg < nseg; seg++){
    const ushort* Abase; const ushort* Bbase; int ldA, ldB, Ks;
    if (seg == 0){
      Abase = A + (size_t)m0 * K; ldA = K; Bbase = Wt; ldB = K; Ks = K;
    } else {
      Abase = (res1 && m0 >= Mhalf) ? (A2_1 + (size_t)(m0 - Mhalf) * K2)
                                    : (A2_0 + (size_t)m0 * K2);
      ldA = K2; Bbase = W2t; ldB = K2; Ks = K2;
    }
    for (int k0 = 0; k0 < Ks; k0 += 32){
      #pragma unroll
      for (int q = 0; q < 2; q++){
        int r16 = wave*32 + q*16;
        int row = r16 + srow;
        int sch = scp ^ ((row >> 1) & 3);
        glds16(Abase + (size_t)row * ldA + k0 + sch*8, &Asm[r16*32]);
        int rbn = n0 + row; if (rbn > N-1) rbn = N-1;
        glds16(Bbase + (size_t)rbn * ldB + k0 + sch*8, &Bsm[r16*32]);
      }
      __syncthreads();
      s16x8 af[4], bf[4];
      #pragma unroll
      for (int f = 0; f < 4; f++){
        int ra = wrow*64 + f*16 + lr;
        af[f] = *reinterpret_cast<const s16x8*>(&Asm[ra*32 + ((ks ^ ((ra>>1)&3))<<3)]);
        int rbn = wcol*64 + f*16 + lr;
        bf[f] = *reinterpret_cast<const s16x8*>(&Bsm[rbn*32 + ((ks ^ ((rbn>>1)&3))<<3)]);
      }
      #pragma unroll
      for (int i = 0; i < 4; i++)
        #pragma unroll
        for (int j = 0; j < 4; j++)
          acc[i][j] = __builtin_amdgcn_mfma_f32_16x16x32_bf16(af[i], bf[j], acc[i][j], 0, 0, 0);
      __syncthreads();
    }
  }
  #pragma unroll
  for (int i = 0; i < 4; i++){
    int mb = m0 + wrow*64 + i*16 + ks*4;
    #pragma unroll
    for (int j = 0; j < 4; j++){
      int n = n0 + wcol*64 + j*16 + lr;
      if (n >= N) continue;
      float bv = (bias ? bias[n] : 0.0f) + (bias2 ? bias2[n] : 0.0f);
      #pragma unroll
      for (int r = 0; r < 4; r++){
        int mrow = mb + r;
        float v = acc[i][j][r] + bv;
        if (GELU) v = 0.5f * v * (1.0f + erff(v * 0.70710678118654752f));
        if (res0){
          if (res1 && mrow >= Mhalf) v += res1[(size_t)(mrow - Mhalf) * N + n];
          else                       v += res0[(size_t)mrow * N + n];
        }
        if (Cp1 && mrow >= Mhalf){
          size_t idx = (size_t)(mrow - Mhalf) * N + n;
          if (OBF)      ((ushort*)Cp1)[idx] = f2b(v);
          else if (ACC) ((float*)Cp1)[idx] += v;
          else          ((float*)Cp1)[idx]  = v;
        } else {
          size_t idx = (size_t)mrow * N + n;
          if (OBF)      ((ushort*)Cp)[idx] = f2b(v);
          else if (ACC) ((float*)Cp)[idx] += v;
          else          ((float*)Cp)[idx]  = v;
        }
      }
    }
  }
}

// ---------------- standalone MFMA GEMM wrapper ----------------
template<bool GELU, bool ACC, bool OBF>
__global__ __launch_bounds__(256) void mg_k(
    const ushort* __restrict__ A, const ushort* __restrict__ Wt,
    const float* __restrict__ bias, void* __restrict__ Cp,
    int M, int N, int K,
    const float* __restrict__ res0, const float* __restrict__ res1, int Mhalf,
    const ushort* __restrict__ A2_0, const ushort* __restrict__ A2_1,
    const ushort* __restrict__ W2t, int K2, const float* __restrict__ bias2,
    void* __restrict__ Cp1)
{
  __shared__ __align__(16) ushort shm[8192];
  mg_body<GELU,ACC,OBF>(shm, shm + 4096, blockIdx.x, blockIdx.y,
                        A, Wt, bias, Cp, M, N, K, res0, res1, Mhalf,
                        A2_0, A2_1, W2t, K2, bias2, Cp1);
}

// ---------------- fuseA: f32 K+Qt GEMM + bf16 Q|V + adapter-down, one dispatch ----------------
#define FA_F32 1152   // 6 x * 192 y
#define FA_QV  1920   // 12 x * 160 y
__global__ __launch_bounds__(256) void fuseA_k(
    const float* __restrict__ lnf, const float* __restrict__ qkvw,
    float* __restrict__ kf, ushort* __restrict__ kbm,
    const float* __restrict__ lnt, float* __restrict__ qt,
    const ushort* __restrict__ ln1b, const ushort* __restrict__ Wt_q,
    ushort* __restrict__ qvb,
    const ushort* __restrict__ Wt_a1d, const float* __restrict__ a1db,
    ushort* __restrict__ mixhb)
{
  __shared__ __align__(16) float sh[8192];   // 32 KB
  int bid = blockIdx.x;
  if (bid < FA_F32){
    f32gemm_body(sh, sh + 4096, bid % 6, bid / 6,
                 lnf, qkvw + 768, kf, kbm, lnt, qkvw, qt,
                 CC, 2304, CC, 160);
  } else if (bid < FA_F32 + FA_QV){
    int b2 = bid - FA_F32;
    mg_body<false,false,true>((ushort*)sh, (ushort*)sh + 4096, b2 % 12, b2 / 12,
        ln1b, Wt_q, nullptr, qvb, 2*NB*LL, 1536, CC,
        nullptr, nullptr, 0, nullptr, nullptr, nullptr, 0, nullptr, nullptr);
  } else {
    int by = bid - FA_F32 - FA_QV;
    mg_body<true,false,true>((ushort*)sh, (ushort*)sh + 4096, 0, by,
        ln1b, Wt_a1d, a1db, mixhb, 2*NB*LL, ADH, CC,
        nullptr, nullptr, 0, nullptr, nullptr, nullptr, 0, nullptr, nullptr);
  }
}

// ---------------- fuseB: fc1 + adapter2-down ----------------
__global__ __launch_bounds__(256) void fuseB_k(
    const ushort* __restrict__ ln2b, const ushort* __restrict__ Wt_fc1,
    const float* __restrict__ fc1b, ushort* __restrict__ hidb,
    const ushort* __restrict__ Wt_a2d, const float* __restrict__ a2db,
    ushort* __restrict__ mixh2b)
{
  __shared__ __align__(16) ushort shm[8192];
  int bid = blockIdx.x;
  if (bid < 24*122){
    mg_body<true,false,true>(shm, shm + 4096, bid % 24, bid / 24,
        ln2b, Wt_fc1, fc1b, hidb, 2*NB*LP, C4, CC,
        nullptr, nullptr, 0, nullptr, nullptr, nullptr, 0, nullptr, nullptr);
  } else {
    mg_body<true,false,true>(shm, shm + 4096, 0, bid - 24*122,
        ln2b, Wt_a2d, a2db, mixh2b, 2*NB*LP, ADH, CC,
        nullptr, nullptr, 0, nullptr, nullptr, nullptr, 0, nullptr, nullptr);
  }
}

// ---------------- scores bodies ----------------
__device__ __forceinline__ void scorest_body(
    float* shf, int jt, int s, int bh,
    const float* __restrict__ qt, const float* __restrict__ kf,
    float* __restrict__ sc)
{
  float* Qs = shf;             // [16][65]
  float* Ks = shf + 16*65;     // [16][65]
  const int t = threadIdx.x, tx = t & 15, ty = t >> 4;
  const int b = bh / NH, h = bh % NH;
  const int j0 = jt * 64;
  const float* qts = qt + (size_t)s * NB * 64 * CC;
  const float* kfs = kf + (size_t)s * NB * LL * CC;
  const size_t qbase = (size_t)b * 64 * CC + (size_t)h * 64;
  const size_t kbase = (size_t)b * LL * CC + (size_t)h * 64;
  const int lkk = t & 15, lmm = t >> 4;
  float acc[4][4] = {};
  for (int d0 = 0; d0 < DHD; d0 += 16){
    #pragma unroll
    for (int q = 0; q < 4; q++)
      Qs[lkk*65 + lmm + 16*q] = qts[qbase + (size_t)(lmm + 16*q) * CC + d0 + lkk];
    #pragma unroll
    for (int q = 0; q < 4; q++)
      Ks[lkk*65 + lmm + 16*q] = kfs[kbase + (size_t)(j0 + lmm + 16*q) * CC + d0 + lkk];
    __syncthreads();
    #pragma unroll
    for (int kk = 0; kk < 16; kk++){
      float a[4], b2[4];
      #pragma unroll
      for (int i = 0; i < 4; i++) a[i] = Qs[kk*65 + ty*4 + i];
      #pragma unroll
      for (int j = 0; j < 4; j++) b2[j] = Ks[kk*65 + tx*4 + j];
      #pragma unroll
      for (int i = 0; i < 4; i++)
        #pragma unroll
        for (int j = 0; j < 4; j++)
          acc[i][j] = fmaf(a[i], b2[j], acc[i][j]);
    }
    __syncthreads();
  }
  #pragma unroll
  for (int i = 0; i < 4; i++)
    #pragma unroll
    for (int j = 0; j < 4; j++)
      sc[((size_t)bh * LL + ty*4 + i) * LL + j0 + tx*4 + j] = acc[i][j] * 0.125f;
}

__device__ __forceinline__ void sqs_body(
    ushort* Qs, ushort* Ks, int it, int bh, int s,
    const ushort* __restrict__ qv, const ushort* __restrict__ kb,
    float* __restrict__ sc)
{
  const int t = threadIdx.x;
  const int b = bh / NH, h = bh % NH;
  const int w = t >> 6, lane = t & 63;
  const int lr = lane & 15, ks = lane >> 4;
  const int qrow0 = s * NB * LL + b * LL + 64 + it * 64;
  const int krow0 = s * NB * LL + b * LL;

  #pragma unroll
  for (int q = 0; q < 4; q++){
    int idx = t + q*256;
    int row = idx >> 4, dv = idx & 15;
    *reinterpret_cast<ushort4*>(&Qs[row*72 + dv*4]) =
      *reinterpret_cast<const ushort4*>(qv + (size_t)(qrow0 + row) * 1536 + h*64 + dv*4);
  }

  f32x4 acc[5][4];
  #pragma unroll
  for (int jt = 0; jt < 5; jt++)
    #pragma unroll
    for (int n = 0; n < 4; n++)
      #pragma unroll
      for (int r = 0; r < 4; r++) acc[jt][n][r] = 0.f;

  for (int jt = 0; jt < 5; jt++){
    __syncthreads();
    #pragma unroll
    for (int q = 0; q < 4; q++){
      int idx = t + q*256;
      int row = idx >> 4, dv = idx & 15;
      *reinterpret_cast<ushort4*>(&Ks[row*72 + dv*4]) =
        *reinterpret_cast<const ushort4*>(kb + (size_t)(krow0 + jt*64 + row) * CC + h*64 + dv*4);
    }
    __syncthreads();
    #pragma unroll
    for (int n = 0; n < 4; n++)
      #pragma unroll
      for (int kt = 0; kt < 2; kt++){
        s16x8 a  = *reinterpret_cast<const s16x8*>(&Qs[(w*16 + lr)*72 + kt*32 + ks*8]);
        s16x8 bb = *reinterpret_cast<const s16x8*>(&Ks[(n*16 + lr)*72 + kt*32 + ks*8]);
        acc[jt][n] = __builtin_amdgcn_mfma_f32_16x16x32_bf16(a, bb, acc[jt][n], 0, 0, 0);
      }
  }
  #pragma unroll
  for (int jt = 0; jt < 5; jt++)
    #pragma unroll
    for (int n = 0; n < 4; n++)
      #pragma unroll
      for (int r = 0; r < 4; r++) acc[jt][n][r] *= 0.125f;
  #pragma unroll
  for (int r = 0; r < 4; r++){
    float mx = -3.4e38f;
    #pragma unroll
    for (int jt = 0; jt < 5; jt++)
      #pragma unroll
      for (int n = 0; n < 4; n++) mx = fmaxf(mx, acc[jt][n][r]);
    #pragma unroll
    for (int o = 1; o < 16; o <<= 1) mx = fmaxf(mx, __shfl_xor(mx, o, 64));
    float sum = 0.f;
    #pragma unroll
    for (int jt = 0; jt < 5; jt++)
      #pragma unroll
      for (int n = 0; n < 4; n++){
        float e = expf(acc[jt][n][r] - mx);
        acc[jt][n][r] = e; sum += e;
      }
    #pragma unroll
    for (int o = 1; o < 16; o <<= 1) sum += __shfl_xor(sum, o, 64);
    float inv = 1.0f / sum;
    size_t rowbase = ((size_t)bh * LL + 64 + it*64 + w*16 + ks*4 + r) * LL;
    #pragma unroll
    for (int jt = 0; jt < 5; jt++)
      #pragma unroll
      for (int n = 0; n < 4; n++)
        sc[rowbase + jt*64 + n*16 + lr] = acc[jt][n][r] * inv;
  }
}

// fused scores dispatch: scorest (f32 VALU) + sqs (MFMA) co-scheduled
#define SC_T 3840   // 5 jt * 2 s * 384 bh
__global__ __launch_bounds__(256) void scoresf_k(
    const float* __restrict__ qt, const float* __restrict__ kf,
    const ushort* __restrict__ qv, const ushort* __restrict__ kb,
    float* __restrict__ p0, float* __restrict__ p1)
{
  __shared__ __align__(16) ushort shm[2*64*72];   // 18 KB
  int bid = blockIdx.x;
  if (bid < SC_T){
    int jt = bid % 5; int r = bid / 5; int s = r & 1; int bh = r >> 1;
    scorest_body((float*)shm, jt, s, bh, qt, kf, s ? p1 : p0);
  } else {
    int b2 = bid - SC_T;
    int it = b2 & 3; int r = b2 >> 2; int bh = r % (NB*NH); int s = r / (NB*NH);
    sqs_body(shm, shm + 64*72, it, bh, s, qv, kb, s ? p1 : p0);
  }
}

// ---------------- template softmax + f64 partial sums (bit-identical softmax body) ----------------
__global__ __launch_bounds__(256) void softmaxt_k(float* __restrict__ p0,
                                                  float* __restrict__ p1,
                                                  double* __restrict__ pp){
  __shared__ float a4[4][256];
  const int lane = threadIdx.x & 63;
  const int w = threadIdx.x >> 6;
  const int s = blockIdx.x / (NB*NH*16);
  const int bx = blockIdx.x % (NB*NH*16);
  const int bh = bx >> 4;
  const int i0 = (bx & 15) * 4;
  float* sc = s ? p1 : p0;
  const size_t row = (size_t)bh * LL + i0 + w;
  float* sr = sc + row * LL;
  float v[5]; float mx = -3.4e38f;
  #pragma unroll
  for (int i = 0; i < 5; i++){ v[i] = sr[lane + 64*i]; mx = fmaxf(mx, v[i]); }
  #pragma unroll
  for (int o = 32; o > 0; o >>= 1) mx = fmaxf(mx, __shfl_xor(mx, o, 64));
  float s2 = 0.f;
  #pragma unroll
  for (int i = 0; i < 5; i++){ v[i] = expf(v[i] - mx); s2 += v[i]; }
  #pragma unroll
  for (int o = 32; o > 0; o >>= 1) s2 += __shfl_xor(s2, o, 64);
  float inv = 1.0f / s2;
  #pragma unroll
  for (int i = 0; i < 5; i++){
    float p = v[i] * inv;
    sr[lane + 64*i] = p;
    if (i >= 1) a4[w][lane + 64*(i-1)] = p;   // j >= 64 slice
  }
  __syncthreads();
  int t = threadIdx.x;
  double ssum = ((double)a4[0][t] + (double)a4[1][t])
              + ((double)a4[2][t] + (double)a4[3][t]);
  // deterministic order: i ascending (pairwise regroup, f64 — negligible)
  double s0 = (double)a4[0][t];
  s0 += (double)a4[1][t]; s0 += (double)a4[2][t]; s0 += (double)a4[3][t];
  (void)ssum;
  pp[(size_t)blockIdx.x * 256 + t] = s0;
}

// ---------------- attn_t final reduce (deterministic order) ----------------
__global__ __launch_bounds__(256) void attnt2_k(const double* __restrict__ pp,
                                                float* __restrict__ at){
  int g = blockIdx.x;             // 0..2*NB
  int s = g / NB, b = g % NB;
  int j = threadIdx.x;
  double sum = 0.0;
  for (int h = 0; h < NH; h++)
    for (int p = 0; p < 16; p++)
      sum += pp[((size_t)(s*NB*NH + b*NH + h) * 16 + p) * 256 + j];
  at[g * LSN + j] = (float)(sum * (1.0 / 768.0));
}

// ---------------- PV via MFMA, both streams ----------------
__global__ __launch_bounds__(256) void pvm_k(const float* __restrict__ p0,
                                             const float* __restrict__ p1,
                                             const ushort* __restrict__ qv,
                                             ushort* __restrict__ pvb){
  __shared__ ushort Pa[64][72];
  __shared__ ushort Vt[64][72];
  const int t = threadIdx.x;
  const int bh = blockIdx.y, s = blockIdx.z;
  const int b = bh / NH, h = bh % NH;
  const int i0 = blockIdx.x * 64;
  const int w = t >> 6, lane = t & 63;
  const int lr = lane & 15, ks = lane >> 4;
  const float* Ap = (s ? p1 : p0) + (size_t)bh * LL * LL;
  const int vrow0 = s * NB * LL + b * LL;
  ushort* pvs = pvb + (size_t)s * NB * LL * CC;

  f32x4 acc[4];
  #pragma unroll
  for (int n = 0; n < 4; n++)
    #pragma unroll
    for (int r = 0; r < 4; r++) acc[n][r] = 0.f;

  for (int jt = 0; jt < 5; jt++){
    int j0 = jt * 64;
    #pragma unroll
    for (int q = 0; q < 4; q++){
      int idx = t + q*256;
      int i = idx >> 4, jv = idx & 15;
      float4 v = *reinterpret_cast<const float4*>(Ap + (size_t)(i0 + i) * LL + j0 + jv*4);
      ushort4 u; u.x = f2b(v.x); u.y = f2b(v.y); u.z = f2b(v.z); u.w = f2b(v.w);
      *reinterpret_cast<ushort4*>(&Pa[i][jv*4]) = u;
    }
    #pragma unroll
    for (int q = 0; q < 4; q++){
      int idx = t + q*256;
      int j = idx >> 4, dv = idx & 15;
      ushort4 u = *reinterpret_cast<const ushort4*>(
          qv + (size_t)(vrow0 + j0 + j) * 1536 + 768 + h*64 + dv*4);
      Vt[dv*4+0][j] = u.x; Vt[dv*4+1][j] = u.y;
      Vt[dv*4+2][j] = u.z; Vt[dv*4+3][j] = u.w;
    }
    __syncthreads();
    #pragma unroll
    for (int n = 0; n < 4; n++)
      #pragma unroll
      for (int kt = 0; kt < 2; kt++){
        s16x8 a = *reinterpret_cast<const s16x8*>(&Pa[w*16 + lr][kt*32 + ks*8]);
        s16x8 bb = *reinterpret_cast<const s16x8*>(&Vt[n*16 + lr][kt*32 + ks*8]);
        acc[n] = __builtin_amdgcn_mfma_f32_16x16x32_bf16(a, bb, acc[n], 0, 0, 0);
      }
    __syncthreads();
  }
  #pragma unroll
  for (int n = 0; n < 4; n++)
    #pragma unroll
    for (int r = 0; r < 4; r++){
      int i = w*16 + ks*4 + r;
      int d = n*16 + lr;
      pvs[(size_t)(b * LL + i0 + i) * 768 + h*64 + d] = f2b(acc[n][r]);
    }
}

// ---------------- CE (identity init folded into rank) ----------------
__global__ __launch_bounds__(256) void ce_rank_k(const float* __restrict__ at,
                                                 int* __restrict__ ordbuf){
  __shared__ float a[256];
  __shared__ int ord[256];
  int b = blockIdx.x, t = threadIdx.x;
  a[t] = at[b * LSN + t];
  ord[t] = t;
  __syncthreads();
  float mine = a[t];
  int rank = 0;
  for (int k = 0; k < 256; k++){
    float ak = a[k];
    rank += (ak > mine) || (ak == mine && k < t);
  }
  if (rank >= 0 && rank < 256) ord[rank] = t;
  __syncthreads();
  ordbuf[(size_t)b * LSN + t] = ord[t];
}

__global__ __launch_bounds__(256) void ce_emit2_k(const int* __restrict__ ordbuf,
                                                  const int* __restrict__ g0,
                                                  const int* __restrict__ g1,
                                                  const int* __restrict__ t0,
                                                  const int* __restrict__ t1,
                                                  float* __restrict__ keep0,
                                                  float* __restrict__ keep1,
                                                  float* __restrict__ rem0,
                                                  float* __restrict__ rem1,
                                                  float* __restrict__ git0,
                                                  float* __restrict__ git1){
  int g = blockIdx.x, t = threadIdx.x;
  int s = g / NB, b = g % NB;
  const int* gidx = s ? g1 : g0;
  const int* gt   = s ? t1 : t0;
  float* out_keep = s ? keep1 : keep0;
  float* out_rem  = s ? rem1 : rem0;
  float* out_git  = s ? git1 : git0;
  int o = ordbuf[(size_t)g * LSN + t];
  o = min(max(o, 0), 255);
  int idx = gidx[b * LSN + o];
  if (t < NKEEP) out_keep[b * NKEEP + t] = (float)idx;
  else           out_rem[b * NREM + (t - NKEEP)] = (float)idx;
  if (t < LT)    out_git[b * LT + t] = (float)gt[b * LT + t];
}

// ---------------- gather, both streams ----------------
__global__ __launch_bounds__(256) void gather_k(const float* __restrict__ xnew,
                                                const int* __restrict__ ordbuf,
                                                float* __restrict__ x2){
  int g = blockIdx.x;
  int s = g / (NB*LP), r0 = g % (NB*LP);
  int b = r0 / LP, r = r0 % LP;
  int o = (r < LT) ? 0 : ordbuf[(size_t)(s*NB + b) * LSN + (r - LT)];
  o = min(max(o, 0), 255);
  int src = (r < LT) ? r : (LT + o);
  const float* sp = xnew + (size_t)s * NB * LL * CC + ((size_t)b * LL + src) * CC;
  float* d = x2 + (size_t)s * NB * LP * CC + (size_t)r0 * CC;
  for (int i = threadIdx.x; i < CC; i += 256) d[i] = sp[i];
}

// ---------------- merged weight transpose+convert ----------------
struct TJ { const float* W; ushort* Wt; int K, N, ldw, colOff, blk0; };
struct TJobs { TJ j[9]; };
__global__ __launch_bounds__(256) void tconvm_k(TJobs jobs){
  __shared__ float tile[32][33];
  int bid = blockIdx.x;
  int ji = 0;
  #pragma unroll
  for (int i = 1; i < 9; i++) if (bid >= jobs.j[i].blk0) ji = i;
  TJ jb = jobs.j[ji];
  int local = bid - jb.blk0;
  int txl = jb.N / 32;
  int n0 = (local % txl) * 32, k0 = (local / txl) * 32;
  int t = threadIdx.x;
  int tx = t & 31, ty = t >> 5;
  #pragma unroll
  for (int q = 0; q < 4; q++)
    tile[ty + 8*q][tx] = jb.W[(size_t)(k0 + ty + 8*q) * jb.ldw + jb.colOff + n0 + tx];
  __syncthreads();
  #pragma unroll
  for (int q = 0; q < 4; q++)
    jb.Wt[(size_t)(n0 + ty + 8*q) * jb.K + k0 + tx] = f2b(tile[tx][ty + 8*q]);
}

__global__ void sentinel_k(float* __restrict__ d, float val, int n){
  int i = blockIdx.x * 256 + threadIdx.x;
  if (i < n) d[i] = val;
}

// ======================================================================
extern "C" void kernel_launch(void* const* d_in, const int* in_sizes, int n_in,
                              void* d_out, int out_size, void* d_ws, size_t ws_size,
                              hipStream_t stream) {
  float* out = (float*)d_out;
  float* ws  = (float*)d_ws;

  static const int EXP[26] = {
    7864320, 7864320, 2048, 2048, 8192, 8192, 1,
    768, 768, 1769472, 589824, 768, 768, 768,
    2359296, 3072, 2359296, 768,
    49152, 64, 49152, 768, 49152, 64, 49152, 768 };

  const void* P[26];
  bool ok = false;
  if (n_in == 26){
    bool m = true; int bad = -1;
    for (int i = 0; i < 26; i++) if (in_sizes[i] != EXP[i]){ m = false; bad = i; break; }
    if (m){ for (int i = 0; i < 26; i++) P[i] = d_in[i]; ok = true; }
    else { sentinel_k<<<16, 256, 0, stream>>>(out, 20000.0f + 16.0f*bad, 4096); return; }
  } else if (n_in == 25){
    bool m = true; int bad = -1;
    for (int i = 0; i < 25; i++){
      int j = (i < 6) ? i : i + 1;
      if (in_sizes[i] != EXP[j]){ m = false; bad = i; break; }
    }
    if (m){
      for (int j = 0; j < 26; j++) P[j] = (j == 6) ? nullptr : d_in[(j < 6) ? j : j - 1];
      ok = true;
    } else { sentinel_k<<<16, 256, 0, stream>>>(out, 20000.0f + 16.0f*bad, 4096); return; }
  }
  if (!ok){ sentinel_k<<<16, 256, 0, stream>>>(out, 10000.0f + 8.0f*n_in, 4096); return; }
  if (out_size != 90656768){
    sentinel_k<<<16, 256, 0, stream>>>(out, 60000.0f + (float)(out_size / 1000000), 4096); return;
  }

  const float* x      = (const float*)P[0];
  const float* xi     = (const float*)P[1];
  const int*   gi_t   = (const int*)P[2];
  const int*   gi_ti  = (const int*)P[3];
  const int*   gi_s   = (const int*)P[4];
  const int*   gi_si  = (const int*)P[5];
  const float* n1_g   = (const float*)P[7];
  const float* n1_b   = (const float*)P[8];
  const float* qkv_w  = (const float*)P[9];
  const float* proj_w = (const float*)P[10];
  const float* proj_b = (const float*)P[11];
  const float* n2_g   = (const float*)P[12];
  const float* n2_b   = (const float*)P[13];
  const float* fc1_w  = (const float*)P[14];
  const float* fc1_b  = (const float*)P[15];
  const float* fc2_w  = (const float*)P[16];
  const float* fc2_b  = (const float*)P[17];
  const float* ad1_dw = (const float*)P[18];
  const float* ad1_db = (const float*)P[19];
  const float* ad1_uw = (const float*)P[20];
  const float* ad1_ub = (const float*)P[21];
  const float* ad2_dw = (const float*)P[22];
  const float* ad2_db = (const float*)P[23];
  const float* ad2_uw = (const float*)P[24];
  const float* ad2_ub = (const float*)P[25];

  // output offsets (f32 elements)
  const size_t o_x     = 0;
  const size_t o_git   = 5996544;
  const size_t o_gis   = 5998592;
  const size_t o_rem   = 6004352;
  const size_t o_attn  = 6006784;
  const size_t o_xi    = 45328384;
  const size_t o_giti  = 51324928;
  const size_t o_gisi  = 51326976;
  const size_t o_remi  = 51332736;
  const size_t o_iattn = 51335168;

  // workspace layout (f32 units) — ~405 MB (ws proven >= 420 MB in R1-R4)
  const size_t BLC      = (size_t)NB * LL * CC;
  const size_t BPC      = (size_t)NB * LP * CC;
  const size_t off_ln   = 0;
  const size_t off_l1b  = off_ln  + 2*BLC;
  const size_t off_k    = off_l1b + BLC;
  const size_t off_qv   = off_k   + 2*BLC;
  const size_t off_kb   = off_qv  + 2*BLC;
  const size_t off_lnt  = off_kb  + BLC;
  const size_t off_qt   = off_lnt + 3145728;
  const size_t off_xnew = off_qt  + 3145728;
  const size_t off_l2b  = off_xnew+ 2*BLC;
  const size_t off_mixh = off_l2b + BPC;
  const size_t off_att  = off_mixh+ 655360;
  const size_t off_attp = off_att + 16384;
  const size_t off_ord  = off_attp+ 6291456;   // f64 partials: 2*NB*NH*16*256
  const size_t off_wts  = off_ord + 16384;
  const size_t total_f  = off_wts + 3342336;
  if (ws_size < total_f * sizeof(float)){
    sentinel_k<<<16, 256, 0, stream>>>(out, 40000.0f + (float)(ws_size >> 20), 4096);
    return;
  }

  int* ordbuf = (int*)(ws + off_ord);
  double* attp = (double*)(ws + off_attp);
  ushort* wts = (ushort*)(ws + off_wts);
  ushort* Wt_q    = wts;                 // contiguous with Wt_v -> N=1536
  ushort* Wt_v    = wts + 589824;
  ushort* Wt_proj = wts + 1179648;
  ushort* Wt_fc1  = wts + 1769472;
  ushort* Wt_fc2  = wts + 4128768;
  ushort* Wt_a1d  = wts + 6488064;
  ushort* Wt_a1u  = wts + 6537216;
  ushort* Wt_a2d  = wts + 6586368;
  ushort* Wt_a2u  = wts + 6635520;
  ushort* ln1b = (ushort*)(ws + off_l1b);
  ushort* qvb  = (ushort*)(ws + off_qv);
  ushort* kb   = (ushort*)(ws + off_kb);
  ushort* pvb  = (ushort*)(ws + off_k);
  ushort* ln2b = (ushort*)(ws + off_l2b);
  ushort* mixhb= (ushort*)(ws + off_mixh);

  float* p0 = out + o_attn;
  float* p1 = out + o_iattn;

  // ---- merged weight convert+transpose (one dispatch, 6528 blocks) ----
  TJobs tj;
  tj.j[0] = { qkv_w,  Wt_q,    768, 768,  2304, 0,    0 };
  tj.j[1] = { qkv_w,  Wt_v,    768, 768,  2304, 1536, 576 };
  tj.j[2] = { proj_w, Wt_proj, 768, 768,  768,  0,    1152 };
  tj.j[3] = { fc1_w,  Wt_fc1,  768, 3072, 3072, 0,    1728 };
  tj.j[4] = { fc2_w,  Wt_fc2,  3072, 768, 768,  0,    4032 };
  tj.j[5] = { ad1_dw, Wt_a1d,  768, 64,   64,   0,    6336 };
  tj.j[6] = { ad1_uw, Wt_a1u,  64,  768,  768,  0,    6384 };
  tj.j[7] = { ad2_dw, Wt_a2d,  768, 64,   64,   0,    6432 };
  tj.j[8] = { ad2_uw, Wt_a2u,  64,  768,  768,  0,    6480 };
  tconvm_k<<<6528, 256, 0, stream>>>(tj);

  // ---- LN1 both streams (f32 + bf16 + template rows) ----
  ln12_k<<<2*NB*LL, 256, 0, stream>>>(x, xi, NB*LL, n1_g, n1_b,
                                      ws + off_ln, ln1b, ws + off_lnt);

  // ---- fuseA: f32 K+Qt GEMM (VALU) + Q|V MFMA + adapter-down MFMA ----
  fuseA_k<<<FA_F32 + FA_QV + 160, 256, 0, stream>>>(
      ws + off_ln, qkv_w, ws + off_k, kb, ws + off_lnt, ws + off_qt,
      ln1b, Wt_q, qvb, Wt_a1d, ad1_db, mixhb);

  // ---- scores: template f32 + fused spatial QK+softmax, one dispatch ----
  scoresf_k<<<SC_T + 3072, 256, 0, stream>>>(ws + off_qt, ws + off_k, qvb, kb, p0, p1);

  // ---- template softmax + f64 partials, then final attn_t reduce ----
  softmaxt_k<<<2*NB*NH*16, 256, 0, stream>>>(p0, p1, attp);
  attnt2_k<<<2*NB, 256, 0, stream>>>(attp, ws + off_att);

  // ---- PV (pvb overwrites dead K f32 region) ----
  pvm_k<<<dim3(5, NB*NH, 2), 256, 0, stream>>>(p0, p1, qvb, pvb);
  // proj + fused cross-mixer + residual -> xnew
  mg_k<false,false,false><<<dim3(6, 160), 256, 0, stream>>>(
      pvb, Wt_proj, proj_b, ws + off_xnew, 2*NB*LL, CC, CC,
      x, xi, NB*LL,
      mixhb + (size_t)NB*LL*ADH, mixhb, Wt_a1u, ADH, ad1_ub, nullptr);

  // ---- CE ----
  ce_rank_k<<<2*NB, 256, 0, stream>>>(ws + off_att, ordbuf);
  ce_emit2_k<<<2*NB, 256, 0, stream>>>(
      ordbuf, gi_s, gi_si, gi_t, gi_ti,
      out + o_gis, out + o_gisi, out + o_rem, out + o_remi,
      out + o_git, out + o_giti);
  gather_k<<<2*NB*LP, 256, 0, stream>>>(ws + off_xnew, ordbuf, ws + off_ln);

  // ---- Phase B ----
  float* x2  = ws + off_ln;
  float* ln2 = ws + off_xnew;
  ushort* hidb   = (ushort*)(ws + off_k);
  ushort* mixh2b = mixhb;

  ln12_k<<<2*NB*LP, 256, 0, stream>>>(x2, x2, 2*NB*LP, n2_g, n2_b, ln2, ln2b, nullptr);
  // fc1 + adapter2-down, one dispatch
  fuseB_k<<<24*122 + 122, 256, 0, stream>>>(
      ln2b, Wt_fc1, fc1_b, hidb, Wt_a2d, ad2_db, mixh2b);
  // fc2 + fused mixer2 + residual, both streams (Cp/Cp1 split)
  mg_k<false,false,false><<<dim3(6, 122), 256, 0, stream>>>(
      hidb, Wt_fc2, fc2_b, out + o_x, 2*NB*LP, CC, C4,
      x2, x2 + BPC, NB*LP,
      mixh2b + (size_t)NB*LP*ADH, mixh2b, Wt_a2u, ADH, ad2_ub,
      out + o_xi);
}

// Round 15
// 1240.530 us; speedup vs baseline: 1.1017x; 1.1017x over previous
//
#include <hip/hip_runtime.h>
#include <hip/hip_bf16.h>

// Problem constants
#define NB   32
#define LL   320
#define CC   768
#define NH   12
#define DHD  64
#define LT   64
#define LSN  256
#define NKEEP 180
#define NREM  76
#define LP   244
#define ADH  64
#define C4   3072

typedef __attribute__((ext_vector_type(8))) short s16x8;
typedef __attribute__((ext_vector_type(4))) float f32x4;

__device__ __forceinline__ ushort f2b(float f){
  union { __hip_bfloat16 h; ushort u; } cv;
  cv.h = __float2bfloat16(f);
  return cv.u;
}

__device__ __forceinline__ void glds16(const ushort* g, ushort* l){
  __builtin_amdgcn_global_load_lds(
      (const __attribute__((address_space(1))) void*)g,
      (__attribute__((address_space(3))) void*)l, 16, 0, 0);
}

// ---------------- reductions ----------------
__device__ __forceinline__ float blk_sum(float v, float* sh){
  #pragma unroll
  for (int o = 32; o > 0; o >>= 1) v += __shfl_down(v, o, 64);
  int w = threadIdx.x >> 6;
  if ((threadIdx.x & 63) == 0) sh[w] = v;
  __syncthreads();
  float r = sh[0] + sh[1] + sh[2] + sh[3];
  __syncthreads();
  return r;
}

// ---------------- LayerNorm, both streams in one launch ----------------
__global__ __launch_bounds__(256) void ln12_k(const float* __restrict__ x0,
                                              const float* __restrict__ x1,
                                              int rowsplit,
                                              const float* __restrict__ g,
                                              const float* __restrict__ be,
                                              float* __restrict__ y,
                                              ushort* __restrict__ yb,
                                              float* __restrict__ lnt){
  __shared__ float sh[4];
  int row = blockIdx.x;
  const float* xr = (row < rowsplit) ? x0 + (size_t)row * CC
                                     : x1 + (size_t)(row - rowsplit) * CC;
  int t = threadIdx.x;
  float v0 = xr[t], v1 = xr[t + 256], v2 = xr[t + 512];
  float m = blk_sum(v0 + v1 + v2, sh) * (1.0f / 768.0f);
  float d0 = v0 - m, d1 = v1 - m, d2 = v2 - m;
  float var = blk_sum(d0*d0 + d1*d1 + d2*d2, sh) * (1.0f / 768.0f);
  float rs = rsqrtf(var + 1e-5f);
  float o0 = d0 * rs * g[t]       + be[t];
  float o1 = d1 * rs * g[t + 256] + be[t + 256];
  float o2 = d2 * rs * g[t + 512] + be[t + 512];
  float* yr = y + (size_t)row * CC;
  yr[t] = o0; yr[t + 256] = o1; yr[t + 512] = o2;
  if (yb){
    ushort* yr2 = yb + (size_t)row * CC;
    yr2[t] = f2b(o0); yr2[t + 256] = f2b(o1); yr2[t + 512] = f2b(o2);
  }
  if (lnt){
    int i = row % LL;
    if (i < 64){
      float* lr = lnt + ((size_t)(row / LL) * 64 + i) * CC;
      lr[t] = o0; lr[t + 256] = o1; lr[t + 512] = o2;
    }
  }
}

// ---------------- fast f32 GEMM (bit-identical k-order), dual-job, low VGPR ----------------
__global__ __launch_bounds__(256) void gemm2_k(
    const float* __restrict__ A1, const float* __restrict__ W1,
    float* __restrict__ C1, ushort* __restrict__ Cb1,
    const float* __restrict__ A2, const float* __restrict__ W2,
    float* __restrict__ C2,
    int K, int ldw, int ldc, int ysplit)
{
  __shared__ float As[32*128];
  __shared__ float Bs[32*128];
  const int t = threadIdx.x;
  const int tx = t & 15, ty = t >> 4;
  const int n0 = blockIdx.x * 128;
  const int yb = blockIdx.y;
  const float* A; const float* W; float* Cm; ushort* Cb; int m0;
  if (yb < ysplit){ A = A1; W = W1; Cm = C1; Cb = Cb1; m0 = yb * 128; }
  else            { A = A2; W = W2; Cm = C2; Cb = nullptr; m0 = (yb - ysplit) * 128; }

  float acc[8][8] = {};
  for (int k0 = 0; k0 < K; k0 += 32){
    #pragma unroll
    for (int q = 0; q < 4; q++){
      int idx = t + q*256;
      int m = idx & 127, kq = idx >> 7;
      float4 v = *reinterpret_cast<const float4*>(A + (size_t)(m0+m)*K + k0 + kq*4);
      As[(kq*4+0)*128 + m] = v.x; As[(kq*4+1)*128 + m] = v.y;
      As[(kq*4+2)*128 + m] = v.z; As[(kq*4+3)*128 + m] = v.w;
    }
    #pragma unroll
    for (int q = 0; q < 4; q++){
      int idx = t + q*256;
      int kr = idx >> 5, nq = idx & 31;
      float4 v = *reinterpret_cast<const float4*>(W + (size_t)(k0+kr)*ldw + n0 + nq*4);
      *reinterpret_cast<float4*>(&Bs[kr*128 + nq*4]) = v;
    }
    __syncthreads();
    #pragma unroll
    for (int kk = 0; kk < 32; kk++){
      float a[8], b[8];
      *reinterpret_cast<float4*>(&a[0]) = *reinterpret_cast<float4*>(&As[kk*128 + ty*4]);
      *reinterpret_cast<float4*>(&a[4]) = *reinterpret_cast<float4*>(&As[kk*128 + 64 + ty*4]);
      *reinterpret_cast<float4*>(&b[0]) = *reinterpret_cast<float4*>(&Bs[kk*128 + tx*4]);
      *reinterpret_cast<float4*>(&b[4]) = *reinterpret_cast<float4*>(&Bs[kk*128 + 64 + tx*4]);
      #pragma unroll
      for (int i = 0; i < 8; i++)
        #pragma unroll
        for (int j = 0; j < 8; j++)
          acc[i][j] = fmaf(a[i], b[j], acc[i][j]);
    }
    __syncthreads();
  }
  #pragma unroll
  for (int i = 0; i < 8; i++){
    int m = m0 + ty*4 + (i & 3) + (i >> 2) * 64;
    #pragma unroll
    for (int j = 0; j < 8; j++){
      int n = n0 + tx*4 + (j & 3) + (j >> 2) * 64;
      float v = acc[i][j];
      Cm[(size_t)m * ldc + n] = v;
      if (Cb) Cb[(size_t)m * ldc + n] = f2b(v);
    }
  }
}

// ---------------- bf16 MFMA GEMM body ----------------
template<bool GELU, bool ACC, bool OBF>
__device__ __forceinline__ void mg_body(
    ushort* Asm, ushort* Bsm, int bx, int by,
    const ushort* __restrict__ A, const ushort* __restrict__ Wt,
    const float* __restrict__ bias, void* __restrict__ Cp,
    int M, int N, int K,
    const float* __restrict__ res0, const float* __restrict__ res1, int Mhalf,
    const ushort* __restrict__ A2_0, const ushort* __restrict__ A2_1,
    const ushort* __restrict__ W2t, int K2, const float* __restrict__ bias2,
    void* __restrict__ Cp1)
{
  const int t = threadIdx.x;
  const int m0 = by * 128, n0 = bx * 128;
  const int wave = t >> 6, lane = t & 63;
  const int wrow = wave >> 1, wcol = wave & 1;
  const int lr = lane & 15, ks = lane >> 4;
  const int srow = lane >> 2, scp = lane & 3;

  f32x4 acc[4][4];
  #pragma unroll
  for (int i = 0; i < 4; i++)
    #pragma unroll
    for (int j = 0; j < 4; j++)
      #pragma unroll
      for (int r = 0; r < 4; r++) acc[i][j][r] = 0.f;

  const int nseg = W2t ? 2 : 1;
  for (int seg = 0; seg < nseg; seg++){
    const ushort* Abase; const ushort* Bbase; int ldA, ldB, Ks;
    if (seg == 0){
      Abase = A + (size_t)m0 * K; ldA = K; Bbase = Wt; ldB = K; Ks = K;
    } else {
      Abase = (res1 && m0 >= Mhalf) ? (A2_1 + (size_t)(m0 - Mhalf) * K2)
                                    : (A2_0 + (size_t)m0 * K2);
      ldA = K2; Bbase = W2t; ldB = K2; Ks = K2;
    }
    for (int k0 = 0; k0 < Ks; k0 += 32){
      #pragma unroll
      for (int q = 0; q < 2; q++){
        int r16 = wave*32 + q*16;
        int row = r16 + srow;
        int sch = scp ^ ((row >> 1) & 3);
        glds16(Abase + (size_t)row * ldA + k0 + sch*8, &Asm[r16*32]);
        int rbn = n0 + row; if (rbn > N-1) rbn = N-1;
        glds16(Bbase + (size_t)rbn * ldB + k0 + sch*8, &Bsm[r16*32]);
      }
      __syncthreads();
      s16x8 af[4], bf[4];
      #pragma unroll
      for (int f = 0; f < 4; f++){
        int ra = wrow*64 + f*16 + lr;
        af[f] = *reinterpret_cast<const s16x8*>(&Asm[ra*32 + ((ks ^ ((ra>>1)&3))<<3)]);
        int rbn = wcol*64 + f*16 + lr;
        bf[f] = *reinterpret_cast<const s16x8*>(&Bsm[rbn*32 + ((ks ^ ((rbn>>1)&3))<<3)]);
      }
      #pragma unroll
      for (int i = 0; i < 4; i++)
        #pragma unroll
        for (int j = 0; j < 4; j++)
          acc[i][j] = __builtin_amdgcn_mfma_f32_16x16x32_bf16(af[i], bf[j], acc[i][j], 0, 0, 0);
      __syncthreads();
    }
  }
  #pragma unroll
  for (int i = 0; i < 4; i++){
    int mb = m0 + wrow*64 + i*16 + ks*4;
    #pragma unroll
    for (int j = 0; j < 4; j++){
      int n = n0 + wcol*64 + j*16 + lr;
      if (n >= N) continue;
      float bv = (bias ? bias[n] : 0.0f) + (bias2 ? bias2[n] : 0.0f);
      #pragma unroll
      for (int r = 0; r < 4; r++){
        int mrow = mb + r;
        float v = acc[i][j][r] + bv;
        if (GELU) v = 0.5f * v * (1.0f + erff(v * 0.70710678118654752f));
        if (res0){
          if (res1 && mrow >= Mhalf) v += res1[(size_t)(mrow - Mhalf) * N + n];
          else                       v += res0[(size_t)mrow * N + n];
        }
        if (Cp1 && mrow >= Mhalf){
          size_t idx = (size_t)(mrow - Mhalf) * N + n;
          if (OBF)      ((ushort*)Cp1)[idx] = f2b(v);
          else if (ACC) ((float*)Cp1)[idx] += v;
          else          ((float*)Cp1)[idx]  = v;
        } else {
          size_t idx = (size_t)mrow * N + n;
          if (OBF)      ((ushort*)Cp)[idx] = f2b(v);
          else if (ACC) ((float*)Cp)[idx] += v;
          else          ((float*)Cp)[idx]  = v;
        }
      }
    }
  }
}

// ---------------- standalone MFMA GEMM wrapper ----------------
template<bool GELU, bool ACC, bool OBF>
__global__ __launch_bounds__(256) void mg_k(
    const ushort* __restrict__ A, const ushort* __restrict__ Wt,
    const float* __restrict__ bias, void* __restrict__ Cp,
    int M, int N, int K,
    const float* __restrict__ res0, const float* __restrict__ res1, int Mhalf,
    const ushort* __restrict__ A2_0, const ushort* __restrict__ A2_1,
    const ushort* __restrict__ W2t, int K2, const float* __restrict__ bias2,
    void* __restrict__ Cp1)
{
  __shared__ __align__(16) ushort shm[8192];
  mg_body<GELU,ACC,OBF>(shm, shm + 4096, blockIdx.x, blockIdx.y,
                        A, Wt, bias, Cp, M, N, K, res0, res1, Mhalf,
                        A2_0, A2_1, W2t, K2, bias2, Cp1);
}

// ---------------- fuseB: fc1 + adapter2-down (same template instantiation) ----------------
__global__ __launch_bounds__(256) void fuseB_k(
    const ushort* __restrict__ ln2b, const ushort* __restrict__ Wt_fc1,
    const float* __restrict__ fc1b, ushort* __restrict__ hidb,
    const ushort* __restrict__ Wt_a2d, const float* __restrict__ a2db,
    ushort* __restrict__ mixh2b)
{
  __shared__ __align__(16) ushort shm[8192];
  int bid = blockIdx.x;
  if (bid < 24*122){
    mg_body<true,false,true>(shm, shm + 4096, bid % 24, bid / 24,
        ln2b, Wt_fc1, fc1b, hidb, 2*NB*LP, C4, CC,
        nullptr, nullptr, 0, nullptr, nullptr, nullptr, 0, nullptr, nullptr);
  } else {
    mg_body<true,false,true>(shm, shm + 4096, 0, bid - 24*122,
        ln2b, Wt_a2d, a2db, mixh2b, 2*NB*LP, ADH, CC,
        nullptr, nullptr, 0, nullptr, nullptr, nullptr, 0, nullptr, nullptr);
  }
}

// ---------------- fuseQVA: Q|V + adapter1-down (both mg_body, GELU runtime-split ok via template) ----------------
__global__ __launch_bounds__(256) void fuseQVA_k(
    const ushort* __restrict__ ln1b, const ushort* __restrict__ Wt_q,
    ushort* __restrict__ qvb,
    const ushort* __restrict__ Wt_a1d, const float* __restrict__ a1db,
    ushort* __restrict__ mixhb)
{
  __shared__ __align__(16) ushort shm[8192];
  int bid = blockIdx.x;
  if (bid < 12*160){
    mg_body<false,false,true>(shm, shm + 4096, bid % 12, bid / 12,
        ln1b, Wt_q, nullptr, qvb, 2*NB*LL, 1536, CC,
        nullptr, nullptr, 0, nullptr, nullptr, nullptr, 0, nullptr, nullptr);
  } else {
    mg_body<true,false,true>(shm, shm + 4096, 0, bid - 12*160,
        ln1b, Wt_a1d, a1db, mixhb, 2*NB*LL, ADH, CC,
        nullptr, nullptr, 0, nullptr, nullptr, nullptr, 0, nullptr, nullptr);
  }
}

// ---------------- template scores (bit-identical f32): rows < 64, both streams ----------------
__global__ __launch_bounds__(256) void scorest_k(const float* __restrict__ qt,
                                                 const float* __restrict__ kf,
                                                 float* __restrict__ p0,
                                                 float* __restrict__ p1){
  __shared__ float Qs[16][65];
  __shared__ float Ks[16][65];
  const int t = threadIdx.x, tx = t & 15, ty = t >> 4;
  const int s = blockIdx.y;
  const int bh = blockIdx.z; const int b = bh / NH, h = bh % NH;
  const int j0 = blockIdx.x * 64;
  float* sc = s ? p1 : p0;
  const float* qts = qt + (size_t)s * NB * 64 * CC;
  const float* kfs = kf + (size_t)s * NB * LL * CC;
  const size_t qbase = (size_t)b * 64 * CC + (size_t)h * 64;
  const size_t kbase = (size_t)b * LL * CC + (size_t)h * 64;
  const int lkk = t & 15, lmm = t >> 4;
  float acc[4][4] = {};
  for (int d0 = 0; d0 < DHD; d0 += 16){
    #pragma unroll
    for (int q = 0; q < 4; q++)
      Qs[lkk][lmm + 16*q] = qts[qbase + (size_t)(lmm + 16*q) * CC + d0 + lkk];
    #pragma unroll
    for (int q = 0; q < 4; q++)
      Ks[lkk][lmm + 16*q] = kfs[kbase + (size_t)(j0 + lmm + 16*q) * CC + d0 + lkk];
    __syncthreads();
    #pragma unroll
    for (int kk = 0; kk < 16; kk++){
      float a[4], b2[4];
      #pragma unroll
      for (int i = 0; i < 4; i++) a[i] = Qs[kk][ty*4 + i];
      #pragma unroll
      for (int j = 0; j < 4; j++) b2[j] = Ks[kk][tx*4 + j];
      #pragma unroll
      for (int i = 0; i < 4; i++)
        #pragma unroll
        for (int j = 0; j < 4; j++)
          acc[i][j] = fmaf(a[i], b2[j], acc[i][j]);
    }
    __syncthreads();
  }
  #pragma unroll
  for (int i = 0; i < 4; i++)
    #pragma unroll
    for (int j = 0; j < 4; j++)
      sc[((size_t)bh * LL + ty*4 + i) * LL + j0 + tx*4 + j] = acc[i][j] * 0.125f;
}

// ---------------- fused spatial QK^T + softmax, both streams ----------------
__global__ __launch_bounds__(256) void sqs_k(const ushort* __restrict__ qv,
                                             const ushort* __restrict__ kb,
                                             float* __restrict__ p0,
                                             float* __restrict__ p1){
  __shared__ ushort Qs[64][72];
  __shared__ ushort Ks[64][72];
  const int t = threadIdx.x;
  const int it = blockIdx.x, bh = blockIdx.y, s = blockIdx.z;
  const int b = bh / NH, h = bh % NH;
  const int w = t >> 6, lane = t & 63;
  const int lr = lane & 15, ks = lane >> 4;
  float* sc = s ? p1 : p0;
  const int qrow0 = s * NB * LL + b * LL + 64 + it * 64;
  const int krow0 = s * NB * LL + b * LL;

  #pragma unroll
  for (int q = 0; q < 4; q++){
    int idx = t + q*256;
    int row = idx >> 4, dv = idx & 15;
    *reinterpret_cast<ushort4*>(&Qs[row][dv*4]) =
      *reinterpret_cast<const ushort4*>(qv + (size_t)(qrow0 + row) * 1536 + h*64 + dv*4);
  }

  f32x4 acc[5][4];
  #pragma unroll
  for (int jt = 0; jt < 5; jt++)
    #pragma unroll
    for (int n = 0; n < 4; n++)
      #pragma unroll
      for (int r = 0; r < 4; r++) acc[jt][n][r] = 0.f;

  for (int jt = 0; jt < 5; jt++){
    __syncthreads();
    #pragma unroll
    for (int q = 0; q < 4; q++){
      int idx = t + q*256;
      int row = idx >> 4, dv = idx & 15;
      *reinterpret_cast<ushort4*>(&Ks[row][dv*4]) =
        *reinterpret_cast<const ushort4*>(kb + (size_t)(krow0 + jt*64 + row) * CC + h*64 + dv*4);
    }
    __syncthreads();
    #pragma unroll
    for (int n = 0; n < 4; n++)
      #pragma unroll
      for (int kt = 0; kt < 2; kt++){
        s16x8 a  = *reinterpret_cast<const s16x8*>(&Qs[w*16 + lr][kt*32 + ks*8]);
        s16x8 bb = *reinterpret_cast<const s16x8*>(&Ks[n*16 + lr][kt*32 + ks*8]);
        acc[jt][n] = __builtin_amdgcn_mfma_f32_16x16x32_bf16(a, bb, acc[jt][n], 0, 0, 0);
      }
  }
  #pragma unroll
  for (int jt = 0; jt < 5; jt++)
    #pragma unroll
    for (int n = 0; n < 4; n++)
      #pragma unroll
      for (int r = 0; r < 4; r++) acc[jt][n][r] *= 0.125f;
  #pragma unroll
  for (int r = 0; r < 4; r++){
    float mx = -3.4e38f;
    #pragma unroll
    for (int jt = 0; jt < 5; jt++)
      #pragma unroll
      for (int n = 0; n < 4; n++) mx = fmaxf(mx, acc[jt][n][r]);
    #pragma unroll
    for (int o = 1; o < 16; o <<= 1) mx = fmaxf(mx, __shfl_xor(mx, o, 64));
    float sum = 0.f;
    #pragma unroll
    for (int jt = 0; jt < 5; jt++)
      #pragma unroll
      for (int n = 0; n < 4; n++){
        float e = expf(acc[jt][n][r] - mx);
        acc[jt][n][r] = e; sum += e;
      }
    #pragma unroll
    for (int o = 1; o < 16; o <<= 1) sum += __shfl_xor(sum, o, 64);
    float inv = 1.0f / sum;
    size_t rowbase = ((size_t)bh * LL + 64 + it*64 + w*16 + ks*4 + r) * LL;
    #pragma unroll
    for (int jt = 0; jt < 5; jt++)
      #pragma unroll
      for (int n = 0; n < 4; n++)
        sc[rowbase + jt*64 + n*16 + lr] = acc[jt][n][r] * inv;
  }
}

// ---------------- template softmax + f64 partials (bit-identical softmax body) ----------------
__global__ __launch_bounds__(256) void softmaxt_k(float* __restrict__ p0,
                                                  float* __restrict__ p1,
                                                  double* __restrict__ pp){
  __shared__ float a4[4][256];
  const int lane = threadIdx.x & 63;
  const int w = threadIdx.x >> 6;
  const int s = blockIdx.x / (NB*NH*16);
  const int bx = blockIdx.x % (NB*NH*16);
  const int bh = bx >> 4;
  const int i0 = (bx & 15) * 4;
  float* sc = s ? p1 : p0;
  const size_t row = (size_t)bh * LL + i0 + w;
  float* sr = sc + row * LL;
  float v[5]; float mx = -3.4e38f;
  #pragma unroll
  for (int i = 0; i < 5; i++){ v[i] = sr[lane + 64*i]; mx = fmaxf(mx, v[i]); }
  #pragma unroll
  for (int o = 32; o > 0; o >>= 1) mx = fmaxf(mx, __shfl_xor(mx, o, 64));
  float s2 = 0.f;
  #pragma unroll
  for (int i = 0; i < 5; i++){ v[i] = expf(v[i] - mx); s2 += v[i]; }
  #pragma unroll
  for (int o = 32; o > 0; o >>= 1) s2 += __shfl_xor(s2, o, 64);
  float inv = 1.0f / s2;
  #pragma unroll
  for (int i = 0; i < 5; i++){
    float p = v[i] * inv;
    sr[lane + 64*i] = p;
    if (i >= 1) a4[w][lane + 64*(i-1)] = p;
  }
  __syncthreads();
  int t = threadIdx.x;
  double s0 = (double)a4[0][t];
  s0 += (double)a4[1][t]; s0 += (double)a4[2][t]; s0 += (double)a4[3][t];
  pp[(size_t)blockIdx.x * 256 + t] = s0;
}

// ---------------- attn_t final reduce ----------------
__global__ __launch_bounds__(256) void attnt2_k(const double* __restrict__ pp,
                                                float* __restrict__ at){
  int g = blockIdx.x;
  int s = g / NB, b = g % NB;
  int j = threadIdx.x;
  double sum = 0.0;
  for (int h = 0; h < NH; h++)
    for (int p = 0; p < 16; p++)
      sum += pp[((size_t)(s*NB*NH + b*NH + h) * 16 + p) * 256 + j];
  at[g * LSN + j] = (float)(sum * (1.0 / 768.0));
}

// ---------------- PV via MFMA, both streams ----------------
__global__ __launch_bounds__(256) void pvm_k(const float* __restrict__ p0,
                                             const float* __restrict__ p1,
                                             const ushort* __restrict__ qv,
                                             ushort* __restrict__ pvb){
  __shared__ ushort Pa[64][72];
  __shared__ ushort Vt[64][72];
  const int t = threadIdx.x;
  const int bh = blockIdx.y, s = blockIdx.z;
  const int b = bh / NH, h = bh % NH;
  const int i0 = blockIdx.x * 64;
  const int w = t >> 6, lane = t & 63;
  const int lr = lane & 15, ks = lane >> 4;
  const float* Ap = (s ? p1 : p0) + (size_t)bh * LL * LL;
  const int vrow0 = s * NB * LL + b * LL;
  ushort* pvs = pvb + (size_t)s * NB * LL * CC;

  f32x4 acc[4];
  #pragma unroll
  for (int n = 0; n < 4; n++)
    #pragma unroll
    for (int r = 0; r < 4; r++) acc[n][r] = 0.f;

  for (int jt = 0; jt < 5; jt++){
    int j0 = jt * 64;
    #pragma unroll
    for (int q = 0; q < 4; q++){
      int idx = t + q*256;
      int i = idx >> 4, jv = idx & 15;
      float4 v = *reinterpret_cast<const float4*>(Ap + (size_t)(i0 + i) * LL + j0 + jv*4);
      ushort4 u; u.x = f2b(v.x); u.y = f2b(v.y); u.z = f2b(v.z); u.w = f2b(v.w);
      *reinterpret_cast<ushort4*>(&Pa[i][jv*4]) = u;
    }
    #pragma unroll
    for (int q = 0; q < 4; q++){
      int idx = t + q*256;
      int j = idx >> 4, dv = idx & 15;
      ushort4 u = *reinterpret_cast<const ushort4*>(
          qv + (size_t)(vrow0 + j0 + j) * 1536 + 768 + h*64 + dv*4);
      Vt[dv*4+0][j] = u.x; Vt[dv*4+1][j] = u.y;
      Vt[dv*4+2][j] = u.z; Vt[dv*4+3][j] = u.w;
    }
    __syncthreads();
    #pragma unroll
    for (int n = 0; n < 4; n++)
      #pragma unroll
      for (int kt = 0; kt < 2; kt++){
        s16x8 a = *reinterpret_cast<const s16x8*>(&Pa[w*16 + lr][kt*32 + ks*8]);
        s16x8 bb = *reinterpret_cast<const s16x8*>(&Vt[n*16 + lr][kt*32 + ks*8]);
        acc[n] = __builtin_amdgcn_mfma_f32_16x16x32_bf16(a, bb, acc[n], 0, 0, 0);
      }
    __syncthreads();
  }
  #pragma unroll
  for (int n = 0; n < 4; n++)
    #pragma unroll
    for (int r = 0; r < 4; r++){
      int i = w*16 + ks*4 + r;
      int d = n*16 + lr;
      pvs[(size_t)(b * LL + i0 + i) * 768 + h*64 + d] = f2b(acc[n][r]);
    }
}

// ---------------- CE ----------------
__global__ __launch_bounds__(256) void ce_rank_k(const float* __restrict__ at,
                                                 int* __restrict__ ordbuf){
  __shared__ float a[256];
  __shared__ int ord[256];
  int b = blockIdx.x, t = threadIdx.x;
  a[t] = at[b * LSN + t];
  ord[t] = t;
  __syncthreads();
  float mine = a[t];
  int rank = 0;
  for (int k = 0; k < 256; k++){
    float ak = a[k];
    rank += (ak > mine) || (ak == mine && k < t);
  }
  if (rank >= 0 && rank < 256) ord[rank] = t;
  __syncthreads();
  ordbuf[(size_t)b * LSN + t] = ord[t];
}

__global__ __launch_bounds__(256) void ce_emit2_k(const int* __restrict__ ordbuf,
                                                  const int* __restrict__ g0,
                                                  const int* __restrict__ g1,
                                                  const int* __restrict__ t0,
                                                  const int* __restrict__ t1,
                                                  float* __restrict__ keep0,
                                                  float* __restrict__ keep1,
                                                  float* __restrict__ rem0,
                                                  float* __restrict__ rem1,
                                                  float* __restrict__ git0,
                                                  float* __restrict__ git1){
  int g = blockIdx.x, t = threadIdx.x;
  int s = g / NB, b = g % NB;
  const int* gidx = s ? g1 : g0;
  const int* gt   = s ? t1 : t0;
  float* out_keep = s ? keep1 : keep0;
  float* out_rem  = s ? rem1 : rem0;
  float* out_git  = s ? git1 : git0;
  int o = ordbuf[(size_t)g * LSN + t];
  o = min(max(o, 0), 255);
  int idx = gidx[b * LSN + o];
  if (t < NKEEP) out_keep[b * NKEEP + t] = (float)idx;
  else           out_rem[b * NREM + (t - NKEEP)] = (float)idx;
  if (t < LT)    out_git[b * LT + t] = (float)gt[b * LT + t];
}

// ---------------- gather, both streams ----------------
__global__ __launch_bounds__(256) void gather_k(const float* __restrict__ xnew,
                                                const int* __restrict__ ordbuf,
                                                float* __restrict__ x2){
  int g = blockIdx.x;
  int s = g / (NB*LP), r0 = g % (NB*LP);
  int b = r0 / LP, r = r0 % LP;
  int o = (r < LT) ? 0 : ordbuf[(size_t)(s*NB + b) * LSN + (r - LT)];
  o = min(max(o, 0), 255);
  int src = (r < LT) ? r : (LT + o);
  const float* sp = xnew + (size_t)s * NB * LL * CC + ((size_t)b * LL + src) * CC;
  float* d = x2 + (size_t)s * NB * LP * CC + (size_t)r0 * CC;
  for (int i = threadIdx.x; i < CC; i += 256) d[i] = sp[i];
}

// ---------------- merged weight transpose+convert ----------------
struct TJ { const float* W; ushort* Wt; int K, N, ldw, colOff, blk0; };
struct TJobs { TJ j[9]; };
__global__ __launch_bounds__(256) void tconvm_k(TJobs jobs){
  __shared__ float tile[32][33];
  int bid = blockIdx.x;
  int ji = 0;
  #pragma unroll
  for (int i = 1; i < 9; i++) if (bid >= jobs.j[i].blk0) ji = i;
  TJ jb = jobs.j[ji];
  int local = bid - jb.blk0;
  int txl = jb.N / 32;
  int n0 = (local % txl) * 32, k0 = (local / txl) * 32;
  int t = threadIdx.x;
  int tx = t & 31, ty = t >> 5;
  #pragma unroll
  for (int q = 0; q < 4; q++)
    tile[ty + 8*q][tx] = jb.W[(size_t)(k0 + ty + 8*q) * jb.ldw + jb.colOff + n0 + tx];
  __syncthreads();
  #pragma unroll
  for (int q = 0; q < 4; q++)
    jb.Wt[(size_t)(n0 + ty + 8*q) * jb.K + k0 + tx] = f2b(tile[tx][ty + 8*q]);
}

__global__ void sentinel_k(float* __restrict__ d, float val, int n){
  int i = blockIdx.x * 256 + threadIdx.x;
  if (i < n) d[i] = val;
}

// ======================================================================
extern "C" void kernel_launch(void* const* d_in, const int* in_sizes, int n_in,
                              void* d_out, int out_size, void* d_ws, size_t ws_size,
                              hipStream_t stream) {
  float* out = (float*)d_out;
  float* ws  = (float*)d_ws;

  static const int EXP[26] = {
    7864320, 7864320, 2048, 2048, 8192, 8192, 1,
    768, 768, 1769472, 589824, 768, 768, 768,
    2359296, 3072, 2359296, 768,
    49152, 64, 49152, 768, 49152, 64, 49152, 768 };

  const void* P[26];
  bool ok = false;
  if (n_in == 26){
    bool m = true; int bad = -1;
    for (int i = 0; i < 26; i++) if (in_sizes[i] != EXP[i]){ m = false; bad = i; break; }
    if (m){ for (int i = 0; i < 26; i++) P[i] = d_in[i]; ok = true; }
    else { sentinel_k<<<16, 256, 0, stream>>>(out, 20000.0f + 16.0f*bad, 4096); return; }
  } else if (n_in == 25){
    bool m = true; int bad = -1;
    for (int i = 0; i < 25; i++){
      int j = (i < 6) ? i : i + 1;
      if (in_sizes[i] != EXP[j]){ m = false; bad = i; break; }
    }
    if (m){
      for (int j = 0; j < 26; j++) P[j] = (j == 6) ? nullptr : d_in[(j < 6) ? j : j - 1];
      ok = true;
    } else { sentinel_k<<<16, 256, 0, stream>>>(out, 20000.0f + 16.0f*bad, 4096); return; }
  }
  if (!ok){ sentinel_k<<<16, 256, 0, stream>>>(out, 10000.0f + 8.0f*n_in, 4096); return; }
  if (out_size != 90656768){
    sentinel_k<<<16, 256, 0, stream>>>(out, 60000.0f + (float)(out_size / 1000000), 4096); return;
  }

  const float* x      = (const float*)P[0];
  const float* xi     = (const float*)P[1];
  const int*   gi_t   = (const int*)P[2];
  const int*   gi_ti  = (const int*)P[3];
  const int*   gi_s   = (const int*)P[4];
  const int*   gi_si  = (const int*)P[5];
  const float* n1_g   = (const float*)P[7];
  const float* n1_b   = (const float*)P[8];
  const float* qkv_w  = (const float*)P[9];
  const float* proj_w = (const float*)P[10];
  const float* proj_b = (const float*)P[11];
  const float* n2_g   = (const float*)P[12];
  const float* n2_b   = (const float*)P[13];
  const float* fc1_w  = (const float*)P[14];
  const float* fc1_b  = (const float*)P[15];
  const float* fc2_w  = (const float*)P[16];
  const float* fc2_b  = (const float*)P[17];
  const float* ad1_dw = (const float*)P[18];
  const float* ad1_db = (const float*)P[19];
  const float* ad1_uw = (const float*)P[20];
  const float* ad1_ub = (const float*)P[21];
  const float* ad2_dw = (const float*)P[22];
  const float* ad2_db = (const float*)P[23];
  const float* ad2_uw = (const float*)P[24];
  const float* ad2_ub = (const float*)P[25];

  // output offsets (f32 elements)
  const size_t o_x     = 0;
  const size_t o_git   = 5996544;
  const size_t o_gis   = 5998592;
  const size_t o_rem   = 6004352;
  const size_t o_attn  = 6006784;
  const size_t o_xi    = 45328384;
  const size_t o_giti  = 51324928;
  const size_t o_gisi  = 51326976;
  const size_t o_remi  = 51332736;
  const size_t o_iattn = 51335168;

  // workspace layout (f32 units) — ~405 MB
  const size_t BLC      = (size_t)NB * LL * CC;
  const size_t BPC      = (size_t)NB * LP * CC;
  const size_t off_ln   = 0;
  const size_t off_l1b  = off_ln  + 2*BLC;
  const size_t off_k    = off_l1b + BLC;
  const size_t off_qv   = off_k   + 2*BLC;
  const size_t off_kb   = off_qv  + 2*BLC;
  const size_t off_lnt  = off_kb  + BLC;
  const size_t off_qt   = off_lnt + 3145728;
  const size_t off_xnew = off_qt  + 3145728;
  const size_t off_l2b  = off_xnew+ 2*BLC;
  const size_t off_mixh = off_l2b + BPC;
  const size_t off_att  = off_mixh+ 655360;
  const size_t off_attp = off_att + 16384;
  const size_t off_ord  = off_attp+ 6291456;
  const size_t off_wts  = off_ord + 16384;
  const size_t total_f  = off_wts + 3342336;
  if (ws_size < total_f * sizeof(float)){
    sentinel_k<<<16, 256, 0, stream>>>(out, 40000.0f + (float)(ws_size >> 20), 4096);
    return;
  }

  int* ordbuf = (int*)(ws + off_ord);
  double* attp = (double*)(ws + off_attp);
  ushort* wts = (ushort*)(ws + off_wts);
  ushort* Wt_q    = wts;                 // contiguous with Wt_v -> N=1536
  ushort* Wt_v    = wts + 589824;
  ushort* Wt_proj = wts + 1179648;
  ushort* Wt_fc1  = wts + 1769472;
  ushort* Wt_fc2  = wts + 4128768;
  ushort* Wt_a1d  = wts + 6488064;
  ushort* Wt_a1u  = wts + 6537216;
  ushort* Wt_a2d  = wts + 6586368;
  ushort* Wt_a2u  = wts + 6635520;
  ushort* ln1b = (ushort*)(ws + off_l1b);
  ushort* qvb  = (ushort*)(ws + off_qv);
  ushort* kb   = (ushort*)(ws + off_kb);
  ushort* pvb  = (ushort*)(ws + off_k);
  ushort* ln2b = (ushort*)(ws + off_l2b);
  ushort* mixhb= (ushort*)(ws + off_mixh);

  float* p0 = out + o_attn;
  float* p1 = out + o_iattn;

  // ---- merged weight convert+transpose ----
  TJobs tj;
  tj.j[0] = { qkv_w,  Wt_q,    768, 768,  2304, 0,    0 };
  tj.j[1] = { qkv_w,  Wt_v,    768, 768,  2304, 1536, 576 };
  tj.j[2] = { proj_w, Wt_proj, 768, 768,  768,  0,    1152 };
  tj.j[3] = { fc1_w,  Wt_fc1,  768, 3072, 3072, 0,    1728 };
  tj.j[4] = { fc2_w,  Wt_fc2,  3072, 768, 768,  0,    4032 };
  tj.j[5] = { ad1_dw, Wt_a1d,  768, 64,   64,   0,    6336 };
  tj.j[6] = { ad1_uw, Wt_a1u,  64,  768,  768,  0,    6384 };
  tj.j[7] = { ad2_dw, Wt_a2d,  768, 64,   64,   0,    6432 };
  tj.j[8] = { ad2_uw, Wt_a2u,  64,  768,  768,  0,    6480 };
  tconvm_k<<<6528, 256, 0, stream>>>(tj);

  // ---- LN1 both streams ----
  ln12_k<<<2*NB*LL, 256, 0, stream>>>(x, xi, NB*LL, n1_g, n1_b,
                                      ws + off_ln, ln1b, ws + off_lnt);

  // ---- K+Qt f32 (dual-job, bit-identical, low VGPR) ----
  gemm2_k<<<dim3(6, 192), 256, 0, stream>>>(
      ws + off_ln, qkv_w + 768, ws + off_k, kb,
      ws + off_lnt, qkv_w, ws + off_qt,
      CC, 2304, CC, 160);
  // ---- Q|V + adapter1-down (homogeneous MFMA fusion) ----
  fuseQVA_k<<<12*160 + 160, 256, 0, stream>>>(
      ln1b, Wt_q, qvb, Wt_a1d, ad1_db, mixhb);

  // ---- scores: template f32, then fused spatial QK+softmax (separate dispatches) ----
  scorest_k<<<dim3(5, 2, NB*NH), 256, 0, stream>>>(ws + off_qt, ws + off_k, p0, p1);
  sqs_k<<<dim3(4, NB*NH, 2), 256, 0, stream>>>(qvb, kb, p0, p1);

  // ---- template softmax + f64 partials, final attn_t reduce ----
  softmaxt_k<<<2*NB*NH*16, 256, 0, stream>>>(p0, p1, attp);
  attnt2_k<<<2*NB, 256, 0, stream>>>(attp, ws + off_att);

  // ---- PV (pvb overwrites dead K f32 region) ----
  pvm_k<<<dim3(5, NB*NH, 2), 256, 0, stream>>>(p0, p1, qvb, pvb);
  // proj + fused cross-mixer + residual -> xnew
  mg_k<false,false,false><<<dim3(6, 160), 256, 0, stream>>>(
      pvb, Wt_proj, proj_b, ws + off_xnew, 2*NB*LL, CC, CC,
      x, xi, NB*LL,
      mixhb + (size_t)NB*LL*ADH, mixhb, Wt_a1u, ADH, ad1_ub, nullptr);

  // ---- CE ----
  ce_rank_k<<<2*NB, 256, 0, stream>>>(ws + off_att, ordbuf);
  ce_emit2_k<<<2*NB, 256, 0, stream>>>(
      ordbuf, gi_s, gi_si, gi_t, gi_ti,
      out + o_gis, out + o_gisi, out + o_rem, out + o_remi,
      out + o_git, out + o_giti);
  gather_k<<<2*NB*LP, 256, 0, stream>>>(ws + off_xnew, ordbuf, ws + off_ln);

  // ---- Phase B ----
  float* x2  = ws + off_ln;
  float* ln2 = ws + off_xnew;
  ushort* hidb   = (ushort*)(ws + off_k);
  ushort* mixh2b = mixhb;

  ln12_k<<<2*NB*LP, 256, 0, stream>>>(x2, x2, 2*NB*LP, n2_g, n2_b, ln2, ln2b, nullptr);
  // fc1 + adapter2-down (homogeneous MFMA fusion)
  fuseB_k<<<24*122 + 122, 256, 0, stream>>>(
      ln2b, Wt_fc1, fc1_b, hidb, Wt_a2d, ad2_db, mixh2b);
  // fc2 + fused mixer2 + residual, both streams
  mg_k<false,false,false><<<dim3(6, 122), 256, 0, stream>>>(
      hidb, Wt_fc2, fc2_b, out + o_x, 2*NB*LP, CC, C4,
      x2, x2 + BPC, NB*LP,
      mixh2b + (size_t)NB*LP*ADH, mixh2b, Wt_a2u, ADH, ad2_ub,
      out + o_xi);
}